// Round 27
// baseline (305.692 us; speedup 1.0000x reference)
//
#include <hip/hip_runtime.h>

#define T_ 48
#define B_ 32
#define N_ 96
#define E_ 24576
#define BN_ (B_*N_)      // 3072
#define M_ (T_*BN_)      // 147456
#define FIN_ 16
#define H_ 128
#define C_ 500
#define TE_ (T_*E_)      // 1179648
#define EPS_ 1e-5f

typedef _Float16 f16x8 __attribute__((ext_vector_type(8)));
typedef float    f32x4 __attribute__((ext_vector_type(4)));
typedef _Float16 half2v __attribute__((ext_vector_type(2)));

__device__ __forceinline__ ushort f2h(float f) {
    _Float16 h = (_Float16)f;
    union { _Float16 h; ushort u; } v;
    v.h = h;
    return v.u;
}
__device__ __forceinline__ float h2f(ushort u) {
    union { ushort u; _Float16 h; } v;
    v.u = u;
    return (float)v.h;
}
__device__ __forceinline__ half2v pkfma(unsigned int v, unsigned int w, half2v acc) {
#if __has_builtin(__builtin_elementwise_fma)
    return __builtin_elementwise_fma(__builtin_bit_cast(half2v, v),
                                     __builtin_bit_cast(half2v, w), acc);
#else
    half2v hv = __builtin_bit_cast(half2v, v);
    half2v wv = __builtin_bit_cast(half2v, w);
    acc[0] += hv[0]*wv[0];
    acc[1] += hv[1]*wv[1];
    return acc;
#endif
}
__device__ __forceinline__ float dot2pk(unsigned int hbits, unsigned int wbits, float acc) {
#if __has_builtin(__builtin_amdgcn_fdot2)
    return __builtin_amdgcn_fdot2(__builtin_bit_cast(half2v, hbits),
                                  __builtin_bit_cast(half2v, wbits), acc, false);
#else
    half2v hv = __builtin_bit_cast(half2v, hbits);
    half2v wv = __builtin_bit_cast(half2v, wbits);
    acc = fmaf((float)hv[0], (float)wv[0], acc);
    acc = fmaf((float)hv[1], (float)wv[1], acc);
    return acc;
#endif
}
__device__ __forceinline__ float sigm(float x) {
    return 1.f / (1.f + __expf(-x));
}
__device__ __forceinline__ float ftanh(float x) {
    x = fminf(15.f, fmaxf(-15.f, x));
    float e = __expf(2.f * x);
    return (e - 1.f) / (e + 1.f);
}

// ---- merged CSR build (blocks 0..T-1) + weight prep (blocks >= T) ----------
// wpk layout (scan thread mapping tid = hh*2 + gp; thread gates: 2gp, 2gp+1):
//   wpk[dir][ab][q][tid] = pack(whh[dir][(2gp+ab)*128+hh][2q], ...[2q+1])
#define WPREP_TOTAL (384+1024+4096+16384+16384+65536+65536+131072+262144)
#define WPREP_BLOCKS ((WPREP_TOTAL + 1023) / 1024)
__global__ __launch_bounds__(1024) void csr_wprep_k(
    const int* __restrict__ ei, int* __restrict__ csr_off,
    unsigned int* __restrict__ csr_pk,
    const float* __restrict__ gcn_b, const float* __restrict__ gam,
    const float* __restrict__ bet, const float* __restrict__ mu,
    const float* __restrict__ var,
    float* __restrict__ bn_sc, float* __restrict__ bn_sh,
    const float* __restrict__ bih0, const float* __restrict__ bhh0,
    float* __restrict__ bias0,
    const float* __restrict__ bih1, const float* __restrict__ bhh1,
    float* __restrict__ bias1,
    const float* __restrict__ gcn_w0, const float* __restrict__ gcn_w12,
    ushort* __restrict__ w0t, ushort* __restrict__ w1t, ushort* __restrict__ w2t,
    const float* __restrict__ whh0, const float* __restrict__ whh1,
    unsigned int* __restrict__ wpk0, unsigned int* __restrict__ wpk1,
    const float* __restrict__ wih0, const float* __restrict__ wih1,
    ushort* __restrict__ wih0b, ushort* __restrict__ wih1b)
{
    __shared__ int cnt[BN_];
    __shared__ int cur[BN_];
    __shared__ int scanbuf[1024];
    __shared__ unsigned int pk[E_];
    int tid = threadIdx.x;

    if (blockIdx.x >= T_) {
        // ---------------- weight-prep blocks (no barriers) ----------------
        int i = (blockIdx.x - T_) * 1024 + tid;
        if (i >= WPREP_TOTAL) return;
        if (i < 384) {
            float sc = gam[i] * rsqrtf(var[i] + EPS_);
            bn_sc[i] = sc;
            bn_sh[i] = gcn_b[i]*sc + bet[i] - mu[i]*sc;
            return;
        }
        i -= 384;
        if (i < 1024) {
            bias0[i] = bih0[i] + bhh0[i];
            bias1[i] = bih1[i] + bhh1[i];
            return;
        }
        i -= 1024;
        if (i < 4096) {       // w0t frag, K=16
            int e = i & 7, lane = (i >> 3) & 63, ct = i >> 9;
            int k = (lane >> 4)*8 + e;
            int c = ct*16 + (lane & 15);
            w0t[i] = (k < 16) ? f2h(gcn_w0[k*128 + c]) : (ushort)0;
            return;
        }
        i -= 4096;
        if (i < 16384) {      // w1t frag, K=128
            int e = i & 7, lane = (i >> 3) & 63, kk = (i >> 9) & 3, ct = i >> 11;
            int k = kk*32 + (lane >> 4)*8 + e;
            int c = ct*16 + (lane & 15);
            w1t[i] = f2h(gcn_w12[k*128 + c]);
            return;
        }
        i -= 16384;
        if (i < 16384) {      // w2t frag
            int e = i & 7, lane = (i >> 3) & 63, kk = (i >> 9) & 3, ct = i >> 11;
            int k = kk*32 + (lane >> 4)*8 + e;
            int c = ct*16 + (lane & 15);
            w2t[i] = f2h(gcn_w12[16384 + k*128 + c]);
            return;
        }
        i -= 16384;
        if (i < 65536) {      // wpk0: [dir][ab2][64 q][256 tid]
            int dir = i >> 15, r = i & 32767;
            int ab = r >> 14, r2 = r & 16383;
            int q = r2 >> 8, tidw = r2 & 255;
            int hh = tidw >> 1, gp = tidw & 1;
            int g = (2*gp + ab)*128 + hh;
            const float* wr = whh0 + ((long)(dir*512 + g))*128 + 2*q;
            wpk0[i] = (unsigned int)f2h(wr[0]) | ((unsigned int)f2h(wr[1]) << 16);
            return;
        }
        i -= 65536;
        if (i < 65536) {      // wpk1
            int dir = i >> 15, r = i & 32767;
            int ab = r >> 14, r2 = r & 16383;
            int q = r2 >> 8, tidw = r2 & 255;
            int hh = tidw >> 1, gp = tidw & 1;
            int g = (2*gp + ab)*128 + hh;
            const float* wr = whh1 + ((long)(dir*512 + g))*128 + 2*q;
            wpk1[i] = (unsigned int)f2h(wr[0]) | ((unsigned int)f2h(wr[1]) << 16);
            return;
        }
        i -= 65536;
        if (i < 131072) {     // wih0b frag, N=512, K=128
            int dir = i >> 16, r = i & 0xFFFF;
            int nt = r >> 11, kk = (r >> 9) & 3, lane = (r >> 3) & 63, e = r & 7;
            int n = nt*16 + (lane & 15);
            int k = kk*32 + (lane >> 4)*8 + e;
            wih0b[i] = f2h(wih0[((long)dir*512 + n)*128 + k]);
            return;
        }
        i -= 131072;
        {                     // wih1b frag, N=512, K=256
            int dir = i >> 17, r = i & 0x1FFFF;
            int nt = r >> 12, kk = (r >> 9) & 7, lane = (r >> 3) & 63, e = r & 7;
            int n = nt*16 + (lane & 15);
            int k = kk*32 + (lane >> 4)*8 + e;
            wih1b[i] = f2h(wih1[((long)dir*512 + n)*256 + k]);
        }
        return;
    }

    // ---------------- CSR-build blocks (one per timestep) ----------------
    int t = blockIdx.x;

    #pragma unroll
    for (int i = 0; i < 3; i++) cnt[tid + i*1024] = 0;
    __syncthreads();

    const int* srcp = ei + ((long)t*2+0)*E_;
    const int* dstp = ei + ((long)t*2+1)*E_;
    #pragma unroll
    for (int i = 0; i < E_/1024; i++)
        atomicAdd(&cnt[dstp[tid + i*1024]], 1);
    __syncthreads();

    int n0 = tid*3;
    int a = cnt[n0], b = cnt[n0+1], c = cnt[n0+2];
    int tot = a + b + c;
    scanbuf[tid] = tot;
    __syncthreads();
    for (int d = 1; d < 1024; d <<= 1) {
        int add = (tid >= d) ? scanbuf[tid-d] : 0;
        __syncthreads();
        scanbuf[tid] += add;
        __syncthreads();
    }
    int excl = scanbuf[tid] - tot;
    cur[n0] = excl; cur[n0+1] = excl + a; cur[n0+2] = excl + a + b;
    int gbase = t*BN_, ebase = t*E_;
    csr_off[gbase+n0]   = ebase + excl;
    csr_off[gbase+n0+1] = ebase + excl + a;
    csr_off[gbase+n0+2] = ebase + excl + a + b;
    if (t == T_-1 && tid == 0) csr_off[M_] = TE_;
    __syncthreads();

    #pragma unroll
    for (int i = 0; i < E_/1024; i++) {
        int e = tid + i*1024;
        int s = srcp[e], d = dstp[e];
        int pos = atomicAdd(&cur[d], 1);
        float w = rsqrtf((float)cnt[s] + 1.f) * rsqrtf((float)cnt[d] + 1.f);
        pk[pos] = (unsigned int)s | ((unsigned int)f2h(w) << 16);
    }
    __syncthreads();

    uint4* dpk = (uint4*)(csr_pk + ebase);
    const uint4* spk = (const uint4*)pk;
    #pragma unroll
    for (int i = 0; i < E_/4096; i++)
        dpk[tid + i*1024] = spk[tid + i*1024];
}

// ---------------- fused GCN layer 1/2: gather(128) + MFMA + BN/ReLU + resid ---
// Block = 64 nodes, 512 threads (8 waves). Gather: 4 passes of wave-per-2-nodes
// (r19-proven body). MFMA: wave pair splits the 8 col-tiles of its row group.
__global__ __launch_bounds__(512) void gcn_layer_k(
    const ushort* __restrict__ h, const ushort* __restrict__ Wt,
    ushort* __restrict__ Cout,
    const int* __restrict__ csr_off, const unsigned int* __restrict__ csr_pk,
    const float* __restrict__ bnsc, const float* __restrict__ bnsh)
{
    __shared__ ushort agg[64][136];
    int nb = gridDim.x;                  // M/64 = 2304, divisible by 8
    int chunk = nb >> 3;
    int bswz = (blockIdx.x & 7) * chunk + (blockIdx.x >> 3);
    int base = bswz * 64;
    int tbase = (base / BN_) * BN_;      // 64-node tile never straddles a timestep
    int wv = threadIdx.x >> 6;           // 0..7
    int lane = threadIdx.x & 63;
    int l2 = lane * 2;

    #pragma unroll
    for (int pass = 0; pass < 4; pass++) {
        int nlA = pass*16 + wv*2;
        int nodeA = __builtin_amdgcn_readfirstlane(base + nlA);
        int e00 = __builtin_amdgcn_readfirstlane(csr_off[nodeA]);
        int e01 = __builtin_amdgcn_readfirstlane(csr_off[nodeA+1]);
        int e11 = __builtin_amdgcn_readfirstlane(csr_off[nodeA+2]);
        int dA = e01 - e00, dB = e11 - e01;
        unsigned int mypkA = (lane < dA) ? csr_pk[e00 + lane] : 0u;
        unsigned int mypkB = (lane < dB) ? csr_pk[e01 + lane] : 0u;
        unsigned int selfA = *(const unsigned int*)(h + (size_t)nodeA*128 + l2);
        unsigned int selfB = *(const unsigned int*)(h + (size_t)(nodeA+1)*128 + l2);

        // self-loop weight 1/(deg+1) from register-resident degree
        ushort swA = f2h(1.0f / (float)(dA + 1));
        ushort swB = f2h(1.0f / (float)(dB + 1));
        half2v spA = __builtin_bit_cast(half2v, (unsigned int)(swA * 0x10001u));
        half2v spB = __builtin_bit_cast(half2v, (unsigned int)(swB * 0x10001u));
        half2v a0 = __builtin_bit_cast(half2v, selfA);
        a0[0] *= spA[0]; a0[1] *= spA[1];
        half2v b0 = __builtin_bit_cast(half2v, selfB);
        b0[0] *= spB[0]; b0[1] *= spB[1];
        half2v a1 = {(_Float16)0.f, (_Float16)0.f}, a2 = a1, a3 = a1;
        half2v b1 = a1, b2 = a1, b3 = a1;

        int cA = (dA < 64) ? dA : 64;
        int cB = (dB < 64) ? dB : 64;
        int cA4 = cA & ~3, cB4 = cB & ~3;
        int cm = (cA4 > cB4) ? cA4 : cB4;
        for (int j = 0; j < cm; j += 4) {
            unsigned int pA0, pA1, pA2, pA3, vA0, vA1, vA2, vA3;
            unsigned int pB0, pB1, pB2, pB3, vB0, vB1, vB2, vB3;
            bool qA = (j < cA4), qB = (j < cB4);
            if (qA) {
                pA0 = (unsigned int)__builtin_amdgcn_readlane((int)mypkA, j+0);
                pA1 = (unsigned int)__builtin_amdgcn_readlane((int)mypkA, j+1);
                pA2 = (unsigned int)__builtin_amdgcn_readlane((int)mypkA, j+2);
                pA3 = (unsigned int)__builtin_amdgcn_readlane((int)mypkA, j+3);
                vA0 = *(const unsigned int*)(h + (size_t)(tbase + (int)(pA0 & 0xffffu))*128 + l2);
                vA1 = *(const unsigned int*)(h + (size_t)(tbase + (int)(pA1 & 0xffffu))*128 + l2);
                vA2 = *(const unsigned int*)(h + (size_t)(tbase + (int)(pA2 & 0xffffu))*128 + l2);
                vA3 = *(const unsigned int*)(h + (size_t)(tbase + (int)(pA3 & 0xffffu))*128 + l2);
            }
            if (qB) {
                pB0 = (unsigned int)__builtin_amdgcn_readlane((int)mypkB, j+0);
                pB1 = (unsigned int)__builtin_amdgcn_readlane((int)mypkB, j+1);
                pB2 = (unsigned int)__builtin_amdgcn_readlane((int)mypkB, j+2);
                pB3 = (unsigned int)__builtin_amdgcn_readlane((int)mypkB, j+3);
                vB0 = *(const unsigned int*)(h + (size_t)(tbase + (int)(pB0 & 0xffffu))*128 + l2);
                vB1 = *(const unsigned int*)(h + (size_t)(tbase + (int)(pB1 & 0xffffu))*128 + l2);
                vB2 = *(const unsigned int*)(h + (size_t)(tbase + (int)(pB2 & 0xffffu))*128 + l2);
                vB3 = *(const unsigned int*)(h + (size_t)(tbase + (int)(pB3 & 0xffffu))*128 + l2);
            }
            if (qA) {
                a0 = pkfma(vA0, (pA0 >> 16) * 0x10001u, a0);
                a1 = pkfma(vA1, (pA1 >> 16) * 0x10001u, a1);
                a2 = pkfma(vA2, (pA2 >> 16) * 0x10001u, a2);
                a3 = pkfma(vA3, (pA3 >> 16) * 0x10001u, a3);
            }
            if (qB) {
                b0 = pkfma(vB0, (pB0 >> 16) * 0x10001u, b0);
                b1 = pkfma(vB1, (pB1 >> 16) * 0x10001u, b1);
                b2 = pkfma(vB2, (pB2 >> 16) * 0x10001u, b2);
                b3 = pkfma(vB3, (pB3 >> 16) * 0x10001u, b3);
            }
        }
        for (int j = cA4; j < cA; j++) {
            unsigned int pk0 = (unsigned int)__builtin_amdgcn_readlane((int)mypkA, j);
            unsigned int v = *(const unsigned int*)(h + (size_t)(tbase + (int)(pk0 & 0xffffu))*128 + l2);
            a0 = pkfma(v, (pk0 >> 16) * 0x10001u, a0);
        }
        for (int j = cB4; j < cB; j++) {
            unsigned int pk0 = (unsigned int)__builtin_amdgcn_readlane((int)mypkB, j);
            unsigned int v = *(const unsigned int*)(h + (size_t)(tbase + (int)(pk0 & 0xffffu))*128 + l2);
            b0 = pkfma(v, (pk0 >> 16) * 0x10001u, b0);
        }
        for (int jj = e00 + 64; jj < e01; jj++) {   // pathological deg > 64
            unsigned int pk0 = __builtin_amdgcn_readfirstlane(csr_pk[jj]);
            unsigned int v = *(const unsigned int*)(h + (size_t)(tbase + (int)(pk0 & 0xffffu))*128 + l2);
            a0 = pkfma(v, (pk0 >> 16) * 0x10001u, a0);
        }
        for (int jj = e01 + 64; jj < e11; jj++) {
            unsigned int pk0 = __builtin_amdgcn_readfirstlane(csr_pk[jj]);
            unsigned int v = *(const unsigned int*)(h + (size_t)(tbase + (int)(pk0 & 0xffffu))*128 + l2);
            b0 = pkfma(v, (pk0 >> 16) * 0x10001u, b0);
        }
        float ra0 = ((float)a0[0] + (float)a1[0]) + ((float)a2[0] + (float)a3[0]);
        float ra1 = ((float)a0[1] + (float)a1[1]) + ((float)a2[1] + (float)a3[1]);
        float rb0 = ((float)b0[0] + (float)b1[0]) + ((float)b2[0] + (float)b3[0]);
        float rb1 = ((float)b0[1] + (float)b1[1]) + ((float)b2[1] + (float)b3[1]);
        *(unsigned int*)&agg[nlA][l2] =
            (unsigned int)f2h(ra0) | ((unsigned int)f2h(ra1) << 16);
        *(unsigned int*)&agg[nlA+1][l2] =
            (unsigned int)f2h(rb0) | ((unsigned int)f2h(rb1) << 16);
    }
    __syncthreads();

    // MFMA phase (K=128 from LDS): wave pair splits 8 col-tiles of row group
    int l16 = lane & 15, lh = lane >> 4;
    int rowgrp = wv >> 1;            // 0..3
    int chalf = (wv & 1) * 4;        // ct base: 0 or 4
    f32x4 acc[4];
    #pragma unroll
    for (int i = 0; i < 4; i++) acc[i] = (f32x4){0.f, 0.f, 0.f, 0.f};
    #pragma unroll
    for (int kk = 0; kk < 4; kk++) {
        f16x8 af = *reinterpret_cast<const f16x8*>(&agg[rowgrp*16 + l16][kk*32 + lh*8]);
        #pragma unroll
        for (int c4 = 0; c4 < 4; c4++) {
            int ct = chalf + c4;
            f16x8 bfr = *reinterpret_cast<const f16x8*>(
                &Wt[(((long)ct*4 + kk)*64 + lane)*8]);
            acc[c4] = __builtin_amdgcn_mfma_f32_16x16x32_f16(af, bfr, acc[c4], 0, 0, 0);
        }
    }
    __syncthreads();   // agg reads done; reuse as transpose buffer

    #pragma unroll
    for (int c4 = 0; c4 < 4; c4++) {
        int col = (chalf + c4)*16 + l16;
        float sc = bnsc[col], sh = bnsh[col];
        #pragma unroll
        for (int r = 0; r < 4; r++) {
            int rl = rowgrp*16 + lh*4 + r;
            float v = acc[c4][r] * sc + sh;
            agg[rl][col] = f2h(fmaxf(v, 0.f));
        }
    }
    __syncthreads();
    long rowblock = (long)base;
    #pragma unroll
    for (int it = 0; it < 2; it++) {
        int s = it*512 + threadIdx.x;   // 1024 segments: 64 rows x 16 (8-col segs)
        int rl = s >> 4, c8 = (s & 15) * 8;
        uint4 v = *(const uint4*)&agg[rl][c8];
        uint4 rv = *(const uint4*)&h[(rowblock + rl)*128 + c8];   // residual = input
        half2v* vv = (half2v*)&v;
        const half2v* rr = (const half2v*)&rv;
        vv[0] += rr[0]; vv[1] += rr[1]; vv[2] += rr[2]; vv[3] += rr[3];
        *(uint4*)&Cout[(rowblock + rl)*128 + c8] = v;
    }
}

// ---------------- fused GCN layer 0: gather(16, f32 in) + MFMA + BN/ReLU -----
__global__ __launch_bounds__(256) void gcn0_k(
    const float* __restrict__ x, const ushort* __restrict__ Wt,
    ushort* __restrict__ Cout,
    const int* __restrict__ csr_off, const unsigned int* __restrict__ csr_pk,
    const float* __restrict__ bnsc, const float* __restrict__ bnsh)
{
    __shared__ ushort agg[64][32];   // K padded to 32, upper half zero
    __shared__ ushort cl[64][136];
    int tid = threadIdx.x;
    int nl = tid >> 2;               // local node
    int fq = tid & 3;
    int f0 = fq*4;
    int node = blockIdx.x*64 + nl;
    int tbase = (node / BN_) * BN_;
    int e0 = csr_off[node], e1 = csr_off[node+1];
    float s = 1.0f / (float)(e1 - e0 + 1);   // self-loop weight 1/(deg+1)
    float4 sv = *(const float4*)(x + (long)node*16 + f0);
    float a0 = sv.x*s, a1 = sv.y*s, a2 = sv.z*s, a3 = sv.w*s;
    int j = e0;
    for (; j + 4 <= e1; j += 4) {
        unsigned int p0 = csr_pk[j], p1 = csr_pk[j+1], p2 = csr_pk[j+2], p3 = csr_pk[j+3];
        int s0 = tbase + (int)(p0 & 0xffffu), s1 = tbase + (int)(p1 & 0xffffu);
        int s2 = tbase + (int)(p2 & 0xffffu), s3 = tbase + (int)(p3 & 0xffffu);
        float w0 = h2f((ushort)(p0 >> 16)), w1 = h2f((ushort)(p1 >> 16));
        float w2 = h2f((ushort)(p2 >> 16)), w3 = h2f((ushort)(p3 >> 16));
        float4 v0 = *(const float4*)(x + (long)s0*16 + f0);
        float4 v1 = *(const float4*)(x + (long)s1*16 + f0);
        float4 v2 = *(const float4*)(x + (long)s2*16 + f0);
        float4 v3 = *(const float4*)(x + (long)s3*16 + f0);
        a0 += v0.x*w0 + v1.x*w1 + v2.x*w2 + v3.x*w3;
        a1 += v0.y*w0 + v1.y*w1 + v2.y*w2 + v3.y*w3;
        a2 += v0.z*w0 + v1.z*w1 + v2.z*w2 + v3.z*w3;
        a3 += v0.w*w0 + v1.w*w1 + v2.w*w2 + v3.w*w3;
    }
    for (; j < e1; j++) {
        unsigned int pk0 = csr_pk[j];
        int sc = tbase + (int)(pk0 & 0xffffu);
        float en = h2f((ushort)(pk0 >> 16));
        float4 v = *(const float4*)(x + (long)sc*16 + f0);
        a0 += v.x*en; a1 += v.y*en; a2 += v.z*en; a3 += v.w*en;
    }
    agg[nl][f0+0] = f2h(a0);
    agg[nl][f0+1] = f2h(a1);
    agg[nl][f0+2] = f2h(a2);
    agg[nl][f0+3] = f2h(a3);
    agg[nl][16+f0+0] = 0;
    agg[nl][16+f0+1] = 0;
    agg[nl][16+f0+2] = 0;
    agg[nl][16+f0+3] = 0;
    __syncthreads();

    // MFMA phase (K=16, KST=1)
    int w = tid >> 6, lane = tid & 63;
    int l16 = lane & 15, lh = lane >> 4;
    f16x8 af = *reinterpret_cast<const f16x8*>(&agg[w*16 + l16][lh*8]);
    f32x4 acc[8];
    #pragma unroll
    for (int i = 0; i < 8; i++) acc[i] = (f32x4){0.f, 0.f, 0.f, 0.f};
    #pragma unroll
    for (int ct = 0; ct < 8; ct++) {
        f16x8 bfr = *reinterpret_cast<const f16x8*>(&Wt[((long)ct*64 + lane)*8]);
        acc[ct] = __builtin_amdgcn_mfma_f32_16x16x32_f16(af, bfr, acc[ct], 0, 0, 0);
    }

    #pragma unroll
    for (int ct = 0; ct < 8; ct++) {
        int col = ct*16 + l16;
        float sc = bnsc[col], sh = bnsh[col];
        #pragma unroll
        for (int r = 0; r < 4; r++) {
            int rl = w*16 + lh*4 + r;
            float v = acc[ct][r] * sc + sh;
            cl[rl][col] = f2h(fmaxf(v, 0.f));
        }
    }
    __syncthreads();
    long rowblock = (long)blockIdx.x * 64;
    #pragma unroll
    for (int it = 0; it < 4; it++) {
        int ss = it*256 + tid;
        int rl = ss >> 4, c8 = (ss & 15) * 8;
        uint4 v = *(const uint4*)&cl[rl][c8];
        *(uint4*)&Cout[(rowblock + rl)*128 + c8] = v;
    }
}

// ---------------- MFMA GEMM: LSTM input projection (frag-swizzled Wt) --------
// Output columns permuted for the scan: colp = (gate&1)*256 + hh*2 + (gate>>1)
template<int K>
__global__ __launch_bounds__(256) void mm_pre_k(
    const ushort* __restrict__ A, const ushort* __restrict__ Wt_all,
    float* __restrict__ Cout_all, const float* __restrict__ bias_all)
{
    constexpr int KST = K/32;
    int dir = blockIdx.z;
    const ushort* Wt = Wt_all + (size_t)dir * 512 * K;
    float* Cout = Cout_all + (size_t)dir * T_ * B_ * 512;
    const float* bias = bias_all + dir * 512;

    int tid = threadIdx.x;
    int w = tid >> 6, lane = tid & 63;
    int l16 = lane & 15, lh = lane >> 4;
    int row0 = blockIdx.x * 64 + w * 16;
    int nt0 = blockIdx.y * 8;

    f32x4 acc[8];
    #pragma unroll
    for (int i = 0; i < 8; i++) acc[i] = (f32x4){0.f, 0.f, 0.f, 0.f};

    #pragma unroll
    for (int kk = 0; kk < KST; kk++) {
        int ka = kk*32 + lh*8;
        f16x8 af = *reinterpret_cast<const f16x8*>(&A[(long)(row0 + l16)*K + ka]);
        #pragma unroll
        for (int ct = 0; ct < 8; ct++) {
            f16x8 bfr = *reinterpret_cast<const f16x8*>(
                &Wt[(((long)(nt0 + ct)*KST + kk)*64 + lane)*8]);
            acc[ct] = __builtin_amdgcn_mfma_f32_16x16x32_f16(af, bfr, acc[ct], 0, 0, 0);
        }
    }

    #pragma unroll
    for (int ct = 0; ct < 8; ct++) {
        int col = (nt0 + ct)*16 + l16;
        float bv = bias[col];
        int gate = col >> 7, hh = col & 127;
        int colp = (gate & 1)*256 + hh*2 + (gate >> 1);   // permuted for scan
        #pragma unroll
        for (int r = 0; r < 4; r++) {
            int row = row0 + lh*4 + r;
            Cout[(long)row*512 + colp] = acc[ct][r] + bv;
        }
    }
}

// ---------------- mean pool (f16 in, f16 out) ----------------

__global__ void meanpool_k(const ushort* __restrict__ h, ushort* __restrict__ embb) {
    int row = blockIdx.x;            // t*B + b
    int t = row / B_, b = row - t*B_;
    int hh = threadIdx.x;
    const ushort* base = h + ((long)t*BN_ + b*N_)*H_ + hh;
    float acc = 0.f;
    for (int n = 0; n < N_; n++) acc += h2f(base[(long)n*H_]);
    embb[(long)row*H_ + hh] = f2h(acc * (1.f / N_));
}

// ---------------- LSTM scan: 256 thr, thread=(hh,gatepair), 1 shfl_xor pair ----
// tid = hh*2 + gp; gp=0 -> gates i,f; gp=1 -> gates g,o. 4 waves, 1 barrier/step.
__global__ __launch_bounds__(256) void lstm_scan_k(
    const float* __restrict__ pre,            // [2][T*B][2][256] permuted
    const unsigned int* __restrict__ wpkbuf,  // [2][2][64][256] packed f16 pairs
    float* __restrict__ out,                  // [T*B][256] f32 (nullable)
    ushort* __restrict__ outb)                // [T*B][256] f16 (nullable)
{
    int dir = blockIdx.x >> 5;
    int b   = blockIdx.x & 31;
    int tid = threadIdx.x;           // hh*2 + gp
    int gp  = tid & 1;
    int hh  = tid >> 1;

    __shared__ ushort hbuf[2][H_];   // double-buffered h (f16)
    ((ushort*)hbuf)[tid] = 0;
    float creg = 0.f;                // consistent across the lane pair

    const unsigned int* wpA = wpkbuf + ((long)dir*2 + 0)*64*256;
    const unsigned int* wpB = wpkbuf + ((long)dir*2 + 1)*64*256;
    unsigned int wA[64], wB[64];
    #pragma unroll
    for (int q = 0; q < 64; q++) {
        wA[q] = wpA[q*256 + tid];
        wB[q] = wpB[q*256 + tid];
    }

    const float* pred = pre + (long)dir * T_ * B_ * 512;
    int t = dir ? (T_ - 1) : 0;
    int tstep = dir ? -1 : 1;
    float pvA = pred[(((long)t*B_ + b)*2 + 0)*256 + tid];
    float pvB = pred[(((long)t*B_ + b)*2 + 1)*256 + tid];
    __syncthreads();

    for (int st = 0; st < T_; st++) {
        int tn = t + tstep;
        tn = (tn < 0) ? 0 : ((tn >= T_) ? T_ - 1 : tn);
        float pvAn = pred[(((long)tn*B_ + b)*2 + 0)*256 + tid];
        float pvBn = pred[(((long)tn*B_ + b)*2 + 1)*256 + tid];

        const uint4* h4 = (const uint4*)hbuf[st & 1];
        float a0 = pvA, a1 = 0.f, a2 = 0.f, a3 = 0.f;
        float c0 = pvB, c1 = 0.f, c2 = 0.f, c3 = 0.f;
        #pragma unroll
        for (int jj = 0; jj < 16; jj++) {
            uint4 hv = h4[jj];
            a0 = dot2pk(hv.x, wA[jj*4+0], a0);
            a1 = dot2pk(hv.y, wA[jj*4+1], a1);
            a2 = dot2pk(hv.z, wA[jj*4+2], a2);
            a3 = dot2pk(hv.w, wA[jj*4+3], a3);
            c0 = dot2pk(hv.x, wB[jj*4+0], c0);
            c1 = dot2pk(hv.y, wB[jj*4+1], c1);
            c2 = dot2pk(hv.z, wB[jj*4+2], c2);
            c3 = dot2pk(hv.w, wB[jj*4+3], c3);
        }
        float sA = (a0 + a1) + (a2 + a3);
        float sB = (c0 + c1) + (c2 + c3);
        float oA = __shfl_xor(sA, 1, 64);
        float oB = __shfl_xor(sB, 1, 64);
        float ig = gp ? oA : sA;
        float fg = gp ? oB : sB;
        float gg = gp ? sA : oA;
        float og = gp ? sB : oB;
        float c = sigm(fg) * creg + sigm(ig) * ftanh(gg);
        float h = sigm(og) * ftanh(c);
        creg = c;
        if (gp == 0) {
            hbuf[(st + 1) & 1][hh] = f2h(h);
            long orow = ((long)t*B_ + b)*256 + dir*H_ + hh;
            if (out)  out[orow] = h;
            if (outb) outb[orow] = f2h(h);
        }
        __syncthreads();
        pvA = pvAn; pvB = pvBn;
        t = tn;
    }
}

// ---------------- fused attention + head: one block per batch graph --------
// Phase 1: stage out2[t][b][:] rows in LDS (48x256 f16 = 24KB).
// Phase 2: hidden u[t][j] over (4 t-phases x 128 j) threads; per-t serial
//          reduce (stride-129 pad keeps it bank-conflict-free).
// Phase 3: softmax-48 (1 thread), weighted pool (256 thr), FC1+FC2+logsoftmax.
__global__ __launch_bounds__(512) void attn_head_k(
    const ushort* __restrict__ out2,
    const float* __restrict__ aw1, const float* __restrict__ ab1,
    const float* __restrict__ aw2, const float* __restrict__ ab2,
    const float* __restrict__ fw1, const float* __restrict__ fb1,
    const float* __restrict__ fw2, const float* __restrict__ fb2,
    float* __restrict__ outp)
{
    int b = blockIdx.x;
    int tid = threadIdx.x;
    __shared__ ushort xs[T_][256];       // 24 KB
    __shared__ float uu[T_][129];        // ~24.2 KB, pad for conflict-free reduce
    __shared__ float wgt[T_];
    __shared__ float ws[256];
    __shared__ float r[128];
    __shared__ float y[C_];
    __shared__ float red[512];

    for (int s = tid; s < T_*32; s += 512) {   // 32 uint4 per 256-f16 row
        int t = s >> 5, q = s & 31;
        ((uint4*)&xs[t][0])[q] = ((const uint4*)(out2 + ((long)t*B_ + b)*256))[q];
    }
    __syncthreads();

    {
        int j = tid & 127;
        int t0 = tid >> 7;               // 0..3
        float w2v = aw2[j];
        for (int t = t0; t < T_; t += 4) {
            float acc = ab1[j];
            for (int k = 0; k < 256; k++)
                acc += h2f(xs[t][k]) * aw1[k*128 + j];
            uu[t][j] = tanhf(acc) * w2v;
        }
    }
    __syncthreads();
    if (tid < T_) {
        float s = 0.f;
        for (int j = 0; j < 128; j++) s += uu[tid][j];
        wgt[tid] = s + ab2[0];
    }
    __syncthreads();
    if (tid == 0) {
        float m = -1e30f;
        for (int t = 0; t < T_; t++) m = fmaxf(m, wgt[t]);
        float s = 0.f;
        for (int t = 0; t < T_; t++) { float e = __expf(wgt[t] - m); wgt[t] = e; s += e; }
        float inv = 1.f / s;
        for (int t = 0; t < T_; t++) wgt[t] *= inv;
    }
    __syncthreads();
    if (tid < 256) {
        float acc = 0.f;
        for (int t = 0; t < T_; t++) acc += wgt[t] * h2f(xs[t][tid]);
        ws[tid] = acc;
    }
    __syncthreads();
    if (tid < 128) {
        float acc = fb1[tid];
        for (int k = 0; k < 256; k++) acc += ws[k] * fw1[k*128 + tid];
        r[tid] = fmaxf(acc, 0.f);
    }
    __syncthreads();
    for (int c = tid; c < C_; c += 512) {
        float acc = fb2[c];
        for (int k = 0; k < 128; k++) acc += r[k] * fw2[k*C_ + c];
        y[c] = acc;
    }
    __syncthreads();
    float m = -1e30f;
    for (int c = tid; c < C_; c += 512) m = fmaxf(m, y[c]);
    red[tid] = m;
    __syncthreads();
    for (int d = 256; d > 0; d >>= 1) {
        if (tid < d) red[tid] = fmaxf(red[tid], red[tid + d]);
        __syncthreads();
    }
    m = red[0];
    __syncthreads();
    float s = 0.f;
    for (int c = tid; c < C_; c += 512) s += __expf(y[c] - m);
    red[tid] = s;
    __syncthreads();
    for (int d = 256; d > 0; d >>= 1) {
        if (tid < d) red[tid] += red[tid + d];
        __syncthreads();
    }
    float lse = m + logf(red[0]);
    for (int c = tid; c < C_; c += 512) outp[(long)b*C_ + c] = y[c] - lse;
}

// ---------------- launch ----------------

extern "C" void kernel_launch(void* const* d_in, const int* in_sizes, int n_in,
                              void* d_out, int out_size, void* d_ws, size_t ws_size,
                              hipStream_t stream) {
    const float* x        = (const float*)d_in[0];
    const int*   ei       = (const int*)d_in[1];
    const float* gcn_w0   = (const float*)d_in[2];
    const float* gcn_w12  = (const float*)d_in[3];
    const float* gcn_b    = (const float*)d_in[4];
    const float* bn_gamma = (const float*)d_in[5];
    const float* bn_beta  = (const float*)d_in[6];
    const float* bn_mean  = (const float*)d_in[7];
    const float* bn_var   = (const float*)d_in[8];
    const float* wih0     = (const float*)d_in[9];
    const float* whh0     = (const float*)d_in[10];
    const float* bih0     = (const float*)d_in[11];
    const float* bhh0     = (const float*)d_in[12];
    const float* wih1     = (const float*)d_in[13];
    const float* whh1     = (const float*)d_in[14];
    const float* bih1     = (const float*)d_in[15];
    const float* bhh1     = (const float*)d_in[16];
    const float* attn_w1  = (const float*)d_in[17];
    const float* attn_b1  = (const float*)d_in[18];
    const float* attn_w2  = (const float*)d_in[19];
    const float* attn_b2  = (const float*)d_in[20];
    const float* fc1_w    = (const float*)d_in[21];
    const float* fc1_b    = (const float*)d_in[22];
    const float* fc2_w    = (const float*)d_in[23];
    const float* fc2_b    = (const float*)d_in[24];

    char* p = (char*)d_ws;
    auto alloc = [&](size_t bytes) {
        void* r = (void*)p;
        p += (bytes + 255) & ~(size_t)255;
        return r;
    };
    ushort* hbA    = (ushort*)alloc((size_t)M_*H_*2);
    ushort* hbB    = (ushort*)alloc((size_t)M_*H_*2);
    int*   csr_off = (int*)  alloc((size_t)(M_+1)*4);
    unsigned int* csr_pk = (unsigned int*)alloc((size_t)TE_*4);
    float* bn_sc   = (float*)alloc(384*4);
    float* bn_sh   = (float*)alloc(384*4);
    float* bias0   = (float*)alloc(1024*4);
    float* bias1   = (float*)alloc(1024*4);
    ushort* w0t    = (ushort*)alloc((size_t)4096*2);
    ushort* w1t    = (ushort*)alloc((size_t)16384*2);
    ushort* w2t    = (ushort*)alloc((size_t)16384*2);
    unsigned int* wpk0 = (unsigned int*)alloc((size_t)2*64*512*4);
    unsigned int* wpk1 = (unsigned int*)alloc((size_t)2*64*512*4);
    ushort* wih0b  = (ushort*)alloc((size_t)2*512*128*2);
    ushort* wih1b  = (ushort*)alloc((size_t)2*512*256*2);
    ushort* embb   = (ushort*)alloc((size_t)T_*B_*H_*2);
    float* pre     = (float*)alloc((size_t)2*T_*B_*512*4);
    ushort* out1b  = (ushort*)alloc((size_t)T_*B_*256*2);
    ushort* out2b  = (ushort*)alloc((size_t)T_*B_*256*2);

    // --- fused CSR build + weight prep in ONE launch (independent work;
    //     wprep blocks fill the 208 CUs csr_build leaves idle) ---
    csr_wprep_k<<<T_ + WPREP_BLOCKS, 1024, 0, stream>>>(
        ei, csr_off, csr_pk,
        gcn_b, bn_gamma, bn_beta, bn_mean, bn_var, bn_sc, bn_sh,
        bih0, bhh0, bias0, bih1, bhh1, bias1,
        gcn_w0, gcn_w12, w0t, w1t, w2t,
        whh0, whh1, wpk0, wpk1,
        wih0, wih1, wih0b, wih1b);

    // --- GCN layer 0 (fully fused: gather + MFMA + BN/ReLU) ---
    gcn0_k<<<M_/64, 256, 0, stream>>>(x, w0t, hbA, csr_off, csr_pk,
                                      bn_sc + 0, bn_sh + 0);
    // --- GCN layer 1 (fused gather + MFMA + BN/ReLU + resid, 8 waves) ---
    gcn_layer_k<<<M_/64, 512, 0, stream>>>(hbA, w1t, hbB, csr_off, csr_pk,
                                           bn_sc + 128, bn_sh + 128);
    // --- GCN layer 2 ---
    gcn_layer_k<<<M_/64, 512, 0, stream>>>(hbB, w2t, hbA, csr_off, csr_pk,
                                           bn_sc + 256, bn_sh + 256);

    // --- mean pool -> embb [T*B,128] f16 ---
    meanpool_k<<<T_*B_, 128, 0, stream>>>(hbA, embb);

    // --- BiLSTM layer 0 ---
    mm_pre_k<128><<<dim3((T_*B_)/64, 4, 2), 256, 0, stream>>>(embb, wih0b, pre, bias0);
    lstm_scan_k<<<64, 256, 0, stream>>>(pre, wpk0, nullptr, out1b);

    // --- BiLSTM layer 1 ---
    mm_pre_k<256><<<dim3((T_*B_)/64, 4, 2), 256, 0, stream>>>(out1b, wih1b, pre, bias1);
    lstm_scan_k<<<64, 256, 0, stream>>>(pre, wpk1, nullptr, out2b);

    // --- fused attention + head (replaces attn_a + attn_pool + head) ---
    attn_head_k<<<B_, 512, 0, stream>>>(out2b,
        attn_w1, attn_b1, attn_w2, attn_b2,
        fc1_w, fc1_b, fc2_w, fc2_b, (float*)d_out);
}

// Round 28
// 265.648 us; speedup vs baseline: 1.1507x; 1.1507x over previous
//
#include <hip/hip_runtime.h>

#define T_ 48
#define B_ 32
#define N_ 96
#define E_ 24576
#define BN_ (B_*N_)      // 3072
#define M_ (T_*BN_)      // 147456
#define FIN_ 16
#define H_ 128
#define C_ 500
#define TE_ (T_*E_)      // 1179648
#define EPS_ 1e-5f

typedef _Float16 f16x8 __attribute__((ext_vector_type(8)));
typedef float    f32x4 __attribute__((ext_vector_type(4)));
typedef _Float16 half2v __attribute__((ext_vector_type(2)));

__device__ __forceinline__ ushort f2h(float f) {
    _Float16 h = (_Float16)f;
    union { _Float16 h; ushort u; } v;
    v.h = h;
    return v.u;
}
__device__ __forceinline__ float h2f(ushort u) {
    union { ushort u; _Float16 h; } v;
    v.u = u;
    return (float)v.h;
}
__device__ __forceinline__ half2v pkfma(unsigned int v, unsigned int w, half2v acc) {
#if __has_builtin(__builtin_elementwise_fma)
    return __builtin_elementwise_fma(__builtin_bit_cast(half2v, v),
                                     __builtin_bit_cast(half2v, w), acc);
#else
    half2v hv = __builtin_bit_cast(half2v, v);
    half2v wv = __builtin_bit_cast(half2v, w);
    acc[0] += hv[0]*wv[0];
    acc[1] += hv[1]*wv[1];
    return acc;
#endif
}
__device__ __forceinline__ float dot2pk(unsigned int hbits, unsigned int wbits, float acc) {
#if __has_builtin(__builtin_amdgcn_fdot2)
    return __builtin_amdgcn_fdot2(__builtin_bit_cast(half2v, hbits),
                                  __builtin_bit_cast(half2v, wbits), acc, false);
#else
    half2v hv = __builtin_bit_cast(half2v, hbits);
    half2v wv = __builtin_bit_cast(half2v, wbits);
    acc = fmaf((float)hv[0], (float)wv[0], acc);
    acc = fmaf((float)hv[1], (float)wv[1], acc);
    return acc;
#endif
}
__device__ __forceinline__ float sigm(float x) {
    return 1.f / (1.f + __expf(-x));
}
__device__ __forceinline__ float ftanh(float x) {
    x = fminf(15.f, fmaxf(-15.f, x));
    float e = __expf(2.f * x);
    return (e - 1.f) / (e + 1.f);
}

// ---- merged CSR build (blocks 0..T-1) + weight prep (blocks >= T) ----------
// wpk layout (scan thread mapping tid = hh*2 + gp; thread gates: 2gp, 2gp+1):
//   wpk[dir][ab][q][tid] = pack(whh[dir][(2gp+ab)*128+hh][2q], ...[2q+1])
#define WPREP_TOTAL (384+1024+4096+16384+16384+65536+65536+131072+262144)
#define WPREP_BLOCKS ((WPREP_TOTAL + 1023) / 1024)
__global__ __launch_bounds__(1024) void csr_wprep_k(
    const int* __restrict__ ei, int* __restrict__ csr_off,
    unsigned int* __restrict__ csr_pk,
    const float* __restrict__ gcn_b, const float* __restrict__ gam,
    const float* __restrict__ bet, const float* __restrict__ mu,
    const float* __restrict__ var,
    float* __restrict__ bn_sc, float* __restrict__ bn_sh,
    const float* __restrict__ bih0, const float* __restrict__ bhh0,
    float* __restrict__ bias0,
    const float* __restrict__ bih1, const float* __restrict__ bhh1,
    float* __restrict__ bias1,
    const float* __restrict__ gcn_w0, const float* __restrict__ gcn_w12,
    ushort* __restrict__ w0t, ushort* __restrict__ w1t, ushort* __restrict__ w2t,
    const float* __restrict__ whh0, const float* __restrict__ whh1,
    unsigned int* __restrict__ wpk0, unsigned int* __restrict__ wpk1,
    const float* __restrict__ wih0, const float* __restrict__ wih1,
    ushort* __restrict__ wih0b, ushort* __restrict__ wih1b)
{
    __shared__ int cnt[BN_];
    __shared__ int cur[BN_];
    __shared__ int scanbuf[1024];
    __shared__ unsigned int pk[E_];
    int tid = threadIdx.x;

    if (blockIdx.x >= T_) {
        // ---------------- weight-prep blocks (no barriers) ----------------
        int i = (blockIdx.x - T_) * 1024 + tid;
        if (i >= WPREP_TOTAL) return;
        if (i < 384) {
            float sc = gam[i] * rsqrtf(var[i] + EPS_);
            bn_sc[i] = sc;
            bn_sh[i] = gcn_b[i]*sc + bet[i] - mu[i]*sc;
            return;
        }
        i -= 384;
        if (i < 1024) {
            bias0[i] = bih0[i] + bhh0[i];
            bias1[i] = bih1[i] + bhh1[i];
            return;
        }
        i -= 1024;
        if (i < 4096) {       // w0t frag, K=16
            int e = i & 7, lane = (i >> 3) & 63, ct = i >> 9;
            int k = (lane >> 4)*8 + e;
            int c = ct*16 + (lane & 15);
            w0t[i] = (k < 16) ? f2h(gcn_w0[k*128 + c]) : (ushort)0;
            return;
        }
        i -= 4096;
        if (i < 16384) {      // w1t frag, K=128
            int e = i & 7, lane = (i >> 3) & 63, kk = (i >> 9) & 3, ct = i >> 11;
            int k = kk*32 + (lane >> 4)*8 + e;
            int c = ct*16 + (lane & 15);
            w1t[i] = f2h(gcn_w12[k*128 + c]);
            return;
        }
        i -= 16384;
        if (i < 16384) {      // w2t frag
            int e = i & 7, lane = (i >> 3) & 63, kk = (i >> 9) & 3, ct = i >> 11;
            int k = kk*32 + (lane >> 4)*8 + e;
            int c = ct*16 + (lane & 15);
            w2t[i] = f2h(gcn_w12[16384 + k*128 + c]);
            return;
        }
        i -= 16384;
        if (i < 65536) {      // wpk0: [dir][ab2][64 q][256 tid]
            int dir = i >> 15, r = i & 32767;
            int ab = r >> 14, r2 = r & 16383;
            int q = r2 >> 8, tidw = r2 & 255;
            int hh = tidw >> 1, gp = tidw & 1;
            int g = (2*gp + ab)*128 + hh;
            const float* wr = whh0 + ((long)(dir*512 + g))*128 + 2*q;
            wpk0[i] = (unsigned int)f2h(wr[0]) | ((unsigned int)f2h(wr[1]) << 16);
            return;
        }
        i -= 65536;
        if (i < 65536) {      // wpk1
            int dir = i >> 15, r = i & 32767;
            int ab = r >> 14, r2 = r & 16383;
            int q = r2 >> 8, tidw = r2 & 255;
            int hh = tidw >> 1, gp = tidw & 1;
            int g = (2*gp + ab)*128 + hh;
            const float* wr = whh1 + ((long)(dir*512 + g))*128 + 2*q;
            wpk1[i] = (unsigned int)f2h(wr[0]) | ((unsigned int)f2h(wr[1]) << 16);
            return;
        }
        i -= 65536;
        if (i < 131072) {     // wih0b frag, N=512, K=128
            int dir = i >> 16, r = i & 0xFFFF;
            int nt = r >> 11, kk = (r >> 9) & 3, lane = (r >> 3) & 63, e = r & 7;
            int n = nt*16 + (lane & 15);
            int k = kk*32 + (lane >> 4)*8 + e;
            wih0b[i] = f2h(wih0[((long)dir*512 + n)*128 + k]);
            return;
        }
        i -= 131072;
        {                     // wih1b frag, N=512, K=256
            int dir = i >> 17, r = i & 0x1FFFF;
            int nt = r >> 12, kk = (r >> 9) & 7, lane = (r >> 3) & 63, e = r & 7;
            int n = nt*16 + (lane & 15);
            int k = kk*32 + (lane >> 4)*8 + e;
            wih1b[i] = f2h(wih1[((long)dir*512 + n)*256 + k]);
        }
        return;
    }

    // ---------------- CSR-build blocks (one per timestep) ----------------
    int t = blockIdx.x;

    #pragma unroll
    for (int i = 0; i < 3; i++) cnt[tid + i*1024] = 0;
    __syncthreads();

    const int* srcp = ei + ((long)t*2+0)*E_;
    const int* dstp = ei + ((long)t*2+1)*E_;
    #pragma unroll
    for (int i = 0; i < E_/1024; i++)
        atomicAdd(&cnt[dstp[tid + i*1024]], 1);
    __syncthreads();

    int n0 = tid*3;
    int a = cnt[n0], b = cnt[n0+1], c = cnt[n0+2];
    int tot = a + b + c;
    scanbuf[tid] = tot;
    __syncthreads();
    for (int d = 1; d < 1024; d <<= 1) {
        int add = (tid >= d) ? scanbuf[tid-d] : 0;
        __syncthreads();
        scanbuf[tid] += add;
        __syncthreads();
    }
    int excl = scanbuf[tid] - tot;
    cur[n0] = excl; cur[n0+1] = excl + a; cur[n0+2] = excl + a + b;
    int gbase = t*BN_, ebase = t*E_;
    csr_off[gbase+n0]   = ebase + excl;
    csr_off[gbase+n0+1] = ebase + excl + a;
    csr_off[gbase+n0+2] = ebase + excl + a + b;
    if (t == T_-1 && tid == 0) csr_off[M_] = TE_;
    __syncthreads();

    #pragma unroll
    for (int i = 0; i < E_/1024; i++) {
        int e = tid + i*1024;
        int s = srcp[e], d = dstp[e];
        int pos = atomicAdd(&cur[d], 1);
        float w = rsqrtf((float)cnt[s] + 1.f) * rsqrtf((float)cnt[d] + 1.f);
        pk[pos] = (unsigned int)s | ((unsigned int)f2h(w) << 16);
    }
    __syncthreads();

    uint4* dpk = (uint4*)(csr_pk + ebase);
    const uint4* spk = (const uint4*)pk;
    #pragma unroll
    for (int i = 0; i < E_/4096; i++)
        dpk[tid + i*1024] = spk[tid + i*1024];
}

// ---------------- fused GCN layer 1/2: gather(128) + MFMA + BN/ReLU + resid ---
// Block = 64 nodes, 512 threads (8 waves). Gather: 4 passes of wave-per-2-nodes
// (r19-proven body). MFMA: wave pair splits the 8 col-tiles of its row group.
__global__ __launch_bounds__(512) void gcn_layer_k(
    const ushort* __restrict__ h, const ushort* __restrict__ Wt,
    ushort* __restrict__ Cout,
    const int* __restrict__ csr_off, const unsigned int* __restrict__ csr_pk,
    const float* __restrict__ bnsc, const float* __restrict__ bnsh)
{
    __shared__ ushort agg[64][136];
    int nb = gridDim.x;                  // M/64 = 2304, divisible by 8
    int chunk = nb >> 3;
    int bswz = (blockIdx.x & 7) * chunk + (blockIdx.x >> 3);
    int base = bswz * 64;
    int tbase = (base / BN_) * BN_;      // 64-node tile never straddles a timestep
    int wv = threadIdx.x >> 6;           // 0..7
    int lane = threadIdx.x & 63;
    int l2 = lane * 2;

    #pragma unroll
    for (int pass = 0; pass < 4; pass++) {
        int nlA = pass*16 + wv*2;
        int nodeA = __builtin_amdgcn_readfirstlane(base + nlA);
        int e00 = __builtin_amdgcn_readfirstlane(csr_off[nodeA]);
        int e01 = __builtin_amdgcn_readfirstlane(csr_off[nodeA+1]);
        int e11 = __builtin_amdgcn_readfirstlane(csr_off[nodeA+2]);
        int dA = e01 - e00, dB = e11 - e01;
        unsigned int mypkA = (lane < dA) ? csr_pk[e00 + lane] : 0u;
        unsigned int mypkB = (lane < dB) ? csr_pk[e01 + lane] : 0u;
        unsigned int selfA = *(const unsigned int*)(h + (size_t)nodeA*128 + l2);
        unsigned int selfB = *(const unsigned int*)(h + (size_t)(nodeA+1)*128 + l2);

        // self-loop weight 1/(deg+1) from register-resident degree
        ushort swA = f2h(1.0f / (float)(dA + 1));
        ushort swB = f2h(1.0f / (float)(dB + 1));
        half2v spA = __builtin_bit_cast(half2v, (unsigned int)(swA * 0x10001u));
        half2v spB = __builtin_bit_cast(half2v, (unsigned int)(swB * 0x10001u));
        half2v a0 = __builtin_bit_cast(half2v, selfA);
        a0[0] *= spA[0]; a0[1] *= spA[1];
        half2v b0 = __builtin_bit_cast(half2v, selfB);
        b0[0] *= spB[0]; b0[1] *= spB[1];
        half2v a1 = {(_Float16)0.f, (_Float16)0.f}, a2 = a1, a3 = a1;
        half2v b1 = a1, b2 = a1, b3 = a1;

        int cA = (dA < 64) ? dA : 64;
        int cB = (dB < 64) ? dB : 64;
        int cA4 = cA & ~3, cB4 = cB & ~3;
        int cm = (cA4 > cB4) ? cA4 : cB4;
        for (int j = 0; j < cm; j += 4) {
            unsigned int pA0, pA1, pA2, pA3, vA0, vA1, vA2, vA3;
            unsigned int pB0, pB1, pB2, pB3, vB0, vB1, vB2, vB3;
            bool qA = (j < cA4), qB = (j < cB4);
            if (qA) {
                pA0 = (unsigned int)__builtin_amdgcn_readlane((int)mypkA, j+0);
                pA1 = (unsigned int)__builtin_amdgcn_readlane((int)mypkA, j+1);
                pA2 = (unsigned int)__builtin_amdgcn_readlane((int)mypkA, j+2);
                pA3 = (unsigned int)__builtin_amdgcn_readlane((int)mypkA, j+3);
                vA0 = *(const unsigned int*)(h + (size_t)(tbase + (int)(pA0 & 0xffffu))*128 + l2);
                vA1 = *(const unsigned int*)(h + (size_t)(tbase + (int)(pA1 & 0xffffu))*128 + l2);
                vA2 = *(const unsigned int*)(h + (size_t)(tbase + (int)(pA2 & 0xffffu))*128 + l2);
                vA3 = *(const unsigned int*)(h + (size_t)(tbase + (int)(pA3 & 0xffffu))*128 + l2);
            }
            if (qB) {
                pB0 = (unsigned int)__builtin_amdgcn_readlane((int)mypkB, j+0);
                pB1 = (unsigned int)__builtin_amdgcn_readlane((int)mypkB, j+1);
                pB2 = (unsigned int)__builtin_amdgcn_readlane((int)mypkB, j+2);
                pB3 = (unsigned int)__builtin_amdgcn_readlane((int)mypkB, j+3);
                vB0 = *(const unsigned int*)(h + (size_t)(tbase + (int)(pB0 & 0xffffu))*128 + l2);
                vB1 = *(const unsigned int*)(h + (size_t)(tbase + (int)(pB1 & 0xffffu))*128 + l2);
                vB2 = *(const unsigned int*)(h + (size_t)(tbase + (int)(pB2 & 0xffffu))*128 + l2);
                vB3 = *(const unsigned int*)(h + (size_t)(tbase + (int)(pB3 & 0xffffu))*128 + l2);
            }
            if (qA) {
                a0 = pkfma(vA0, (pA0 >> 16) * 0x10001u, a0);
                a1 = pkfma(vA1, (pA1 >> 16) * 0x10001u, a1);
                a2 = pkfma(vA2, (pA2 >> 16) * 0x10001u, a2);
                a3 = pkfma(vA3, (pA3 >> 16) * 0x10001u, a3);
            }
            if (qB) {
                b0 = pkfma(vB0, (pB0 >> 16) * 0x10001u, b0);
                b1 = pkfma(vB1, (pB1 >> 16) * 0x10001u, b1);
                b2 = pkfma(vB2, (pB2 >> 16) * 0x10001u, b2);
                b3 = pkfma(vB3, (pB3 >> 16) * 0x10001u, b3);
            }
        }
        for (int j = cA4; j < cA; j++) {
            unsigned int pk0 = (unsigned int)__builtin_amdgcn_readlane((int)mypkA, j);
            unsigned int v = *(const unsigned int*)(h + (size_t)(tbase + (int)(pk0 & 0xffffu))*128 + l2);
            a0 = pkfma(v, (pk0 >> 16) * 0x10001u, a0);
        }
        for (int j = cB4; j < cB; j++) {
            unsigned int pk0 = (unsigned int)__builtin_amdgcn_readlane((int)mypkB, j);
            unsigned int v = *(const unsigned int*)(h + (size_t)(tbase + (int)(pk0 & 0xffffu))*128 + l2);
            b0 = pkfma(v, (pk0 >> 16) * 0x10001u, b0);
        }
        for (int jj = e00 + 64; jj < e01; jj++) {   // pathological deg > 64
            unsigned int pk0 = __builtin_amdgcn_readfirstlane(csr_pk[jj]);
            unsigned int v = *(const unsigned int*)(h + (size_t)(tbase + (int)(pk0 & 0xffffu))*128 + l2);
            a0 = pkfma(v, (pk0 >> 16) * 0x10001u, a0);
        }
        for (int jj = e01 + 64; jj < e11; jj++) {
            unsigned int pk0 = __builtin_amdgcn_readfirstlane(csr_pk[jj]);
            unsigned int v = *(const unsigned int*)(h + (size_t)(tbase + (int)(pk0 & 0xffffu))*128 + l2);
            b0 = pkfma(v, (pk0 >> 16) * 0x10001u, b0);
        }
        float ra0 = ((float)a0[0] + (float)a1[0]) + ((float)a2[0] + (float)a3[0]);
        float ra1 = ((float)a0[1] + (float)a1[1]) + ((float)a2[1] + (float)a3[1]);
        float rb0 = ((float)b0[0] + (float)b1[0]) + ((float)b2[0] + (float)b3[0]);
        float rb1 = ((float)b0[1] + (float)b1[1]) + ((float)b2[1] + (float)b3[1]);
        *(unsigned int*)&agg[nlA][l2] =
            (unsigned int)f2h(ra0) | ((unsigned int)f2h(ra1) << 16);
        *(unsigned int*)&agg[nlA+1][l2] =
            (unsigned int)f2h(rb0) | ((unsigned int)f2h(rb1) << 16);
    }
    __syncthreads();

    // MFMA phase (K=128 from LDS): wave pair splits 8 col-tiles of row group
    int l16 = lane & 15, lh = lane >> 4;
    int rowgrp = wv >> 1;            // 0..3
    int chalf = (wv & 1) * 4;        // ct base: 0 or 4
    f32x4 acc[4];
    #pragma unroll
    for (int i = 0; i < 4; i++) acc[i] = (f32x4){0.f, 0.f, 0.f, 0.f};
    #pragma unroll
    for (int kk = 0; kk < 4; kk++) {
        f16x8 af = *reinterpret_cast<const f16x8*>(&agg[rowgrp*16 + l16][kk*32 + lh*8]);
        #pragma unroll
        for (int c4 = 0; c4 < 4; c4++) {
            int ct = chalf + c4;
            f16x8 bfr = *reinterpret_cast<const f16x8*>(
                &Wt[(((long)ct*4 + kk)*64 + lane)*8]);
            acc[c4] = __builtin_amdgcn_mfma_f32_16x16x32_f16(af, bfr, acc[c4], 0, 0, 0);
        }
    }
    __syncthreads();   // agg reads done; reuse as transpose buffer

    #pragma unroll
    for (int c4 = 0; c4 < 4; c4++) {
        int col = (chalf + c4)*16 + l16;
        float sc = bnsc[col], sh = bnsh[col];
        #pragma unroll
        for (int r = 0; r < 4; r++) {
            int rl = rowgrp*16 + lh*4 + r;
            float v = acc[c4][r] * sc + sh;
            agg[rl][col] = f2h(fmaxf(v, 0.f));
        }
    }
    __syncthreads();
    long rowblock = (long)base;
    #pragma unroll
    for (int it = 0; it < 2; it++) {
        int s = it*512 + threadIdx.x;   // 1024 segments: 64 rows x 16 (8-col segs)
        int rl = s >> 4, c8 = (s & 15) * 8;
        uint4 v = *(const uint4*)&agg[rl][c8];
        uint4 rv = *(const uint4*)&h[(rowblock + rl)*128 + c8];   // residual = input
        half2v* vv = (half2v*)&v;
        const half2v* rr = (const half2v*)&rv;
        vv[0] += rr[0]; vv[1] += rr[1]; vv[2] += rr[2]; vv[3] += rr[3];
        *(uint4*)&Cout[(rowblock + rl)*128 + c8] = v;
    }
}

// ---------------- fused GCN layer 0: gather(16, f32 in) + MFMA + BN/ReLU -----
__global__ __launch_bounds__(256) void gcn0_k(
    const float* __restrict__ x, const ushort* __restrict__ Wt,
    ushort* __restrict__ Cout,
    const int* __restrict__ csr_off, const unsigned int* __restrict__ csr_pk,
    const float* __restrict__ bnsc, const float* __restrict__ bnsh)
{
    __shared__ ushort agg[64][32];   // K padded to 32, upper half zero
    __shared__ ushort cl[64][136];
    int tid = threadIdx.x;
    int nl = tid >> 2;               // local node
    int fq = tid & 3;
    int f0 = fq*4;
    int node = blockIdx.x*64 + nl;
    int tbase = (node / BN_) * BN_;
    int e0 = csr_off[node], e1 = csr_off[node+1];
    float s = 1.0f / (float)(e1 - e0 + 1);   // self-loop weight 1/(deg+1)
    float4 sv = *(const float4*)(x + (long)node*16 + f0);
    float a0 = sv.x*s, a1 = sv.y*s, a2 = sv.z*s, a3 = sv.w*s;
    int j = e0;
    for (; j + 4 <= e1; j += 4) {
        unsigned int p0 = csr_pk[j], p1 = csr_pk[j+1], p2 = csr_pk[j+2], p3 = csr_pk[j+3];
        int s0 = tbase + (int)(p0 & 0xffffu), s1 = tbase + (int)(p1 & 0xffffu);
        int s2 = tbase + (int)(p2 & 0xffffu), s3 = tbase + (int)(p3 & 0xffffu);
        float w0 = h2f((ushort)(p0 >> 16)), w1 = h2f((ushort)(p1 >> 16));
        float w2 = h2f((ushort)(p2 >> 16)), w3 = h2f((ushort)(p3 >> 16));
        float4 v0 = *(const float4*)(x + (long)s0*16 + f0);
        float4 v1 = *(const float4*)(x + (long)s1*16 + f0);
        float4 v2 = *(const float4*)(x + (long)s2*16 + f0);
        float4 v3 = *(const float4*)(x + (long)s3*16 + f0);
        a0 += v0.x*w0 + v1.x*w1 + v2.x*w2 + v3.x*w3;
        a1 += v0.y*w0 + v1.y*w1 + v2.y*w2 + v3.y*w3;
        a2 += v0.z*w0 + v1.z*w1 + v2.z*w2 + v3.z*w3;
        a3 += v0.w*w0 + v1.w*w1 + v2.w*w2 + v3.w*w3;
    }
    for (; j < e1; j++) {
        unsigned int pk0 = csr_pk[j];
        int sc = tbase + (int)(pk0 & 0xffffu);
        float en = h2f((ushort)(pk0 >> 16));
        float4 v = *(const float4*)(x + (long)sc*16 + f0);
        a0 += v.x*en; a1 += v.y*en; a2 += v.z*en; a3 += v.w*en;
    }
    agg[nl][f0+0] = f2h(a0);
    agg[nl][f0+1] = f2h(a1);
    agg[nl][f0+2] = f2h(a2);
    agg[nl][f0+3] = f2h(a3);
    agg[nl][16+f0+0] = 0;
    agg[nl][16+f0+1] = 0;
    agg[nl][16+f0+2] = 0;
    agg[nl][16+f0+3] = 0;
    __syncthreads();

    // MFMA phase (K=16, KST=1)
    int w = tid >> 6, lane = tid & 63;
    int l16 = lane & 15, lh = lane >> 4;
    f16x8 af = *reinterpret_cast<const f16x8*>(&agg[w*16 + l16][lh*8]);
    f32x4 acc[8];
    #pragma unroll
    for (int i = 0; i < 8; i++) acc[i] = (f32x4){0.f, 0.f, 0.f, 0.f};
    #pragma unroll
    for (int ct = 0; ct < 8; ct++) {
        f16x8 bfr = *reinterpret_cast<const f16x8*>(&Wt[((long)ct*64 + lane)*8]);
        acc[ct] = __builtin_amdgcn_mfma_f32_16x16x32_f16(af, bfr, acc[ct], 0, 0, 0);
    }

    #pragma unroll
    for (int ct = 0; ct < 8; ct++) {
        int col = ct*16 + l16;
        float sc = bnsc[col], sh = bnsh[col];
        #pragma unroll
        for (int r = 0; r < 4; r++) {
            int rl = w*16 + lh*4 + r;
            float v = acc[ct][r] * sc + sh;
            cl[rl][col] = f2h(fmaxf(v, 0.f));
        }
    }
    __syncthreads();
    long rowblock = (long)blockIdx.x * 64;
    #pragma unroll
    for (int it = 0; it < 4; it++) {
        int ss = it*256 + tid;
        int rl = ss >> 4, c8 = (ss & 15) * 8;
        uint4 v = *(const uint4*)&cl[rl][c8];
        *(uint4*)&Cout[(rowblock + rl)*128 + c8] = v;
    }
}

// ---------------- MFMA GEMM: LSTM input projection (frag-swizzled Wt) --------
// Output columns permuted for the scan: colp = (gate&1)*256 + hh*2 + (gate>>1)
template<int K>
__global__ __launch_bounds__(256) void mm_pre_k(
    const ushort* __restrict__ A, const ushort* __restrict__ Wt_all,
    float* __restrict__ Cout_all, const float* __restrict__ bias_all)
{
    constexpr int KST = K/32;
    int dir = blockIdx.z;
    const ushort* Wt = Wt_all + (size_t)dir * 512 * K;
    float* Cout = Cout_all + (size_t)dir * T_ * B_ * 512;
    const float* bias = bias_all + dir * 512;

    int tid = threadIdx.x;
    int w = tid >> 6, lane = tid & 63;
    int l16 = lane & 15, lh = lane >> 4;
    int row0 = blockIdx.x * 64 + w * 16;
    int nt0 = blockIdx.y * 8;

    f32x4 acc[8];
    #pragma unroll
    for (int i = 0; i < 8; i++) acc[i] = (f32x4){0.f, 0.f, 0.f, 0.f};

    #pragma unroll
    for (int kk = 0; kk < KST; kk++) {
        int ka = kk*32 + lh*8;
        f16x8 af = *reinterpret_cast<const f16x8*>(&A[(long)(row0 + l16)*K + ka]);
        #pragma unroll
        for (int ct = 0; ct < 8; ct++) {
            f16x8 bfr = *reinterpret_cast<const f16x8*>(
                &Wt[(((long)(nt0 + ct)*KST + kk)*64 + lane)*8]);
            acc[ct] = __builtin_amdgcn_mfma_f32_16x16x32_f16(af, bfr, acc[ct], 0, 0, 0);
        }
    }

    #pragma unroll
    for (int ct = 0; ct < 8; ct++) {
        int col = (nt0 + ct)*16 + l16;
        float bv = bias[col];
        int gate = col >> 7, hh = col & 127;
        int colp = (gate & 1)*256 + hh*2 + (gate >> 1);   // permuted for scan
        #pragma unroll
        for (int r = 0; r < 4; r++) {
            int row = row0 + lh*4 + r;
            Cout[(long)row*512 + colp] = acc[ct][r] + bv;
        }
    }
}

// ---------------- mean pool (f16 in, f16 out) ----------------

__global__ void meanpool_k(const ushort* __restrict__ h, ushort* __restrict__ embb) {
    int row = blockIdx.x;            // t*B + b
    int t = row / B_, b = row - t*B_;
    int hh = threadIdx.x;
    const ushort* base = h + ((long)t*BN_ + b*N_)*H_ + hh;
    float acc = 0.f;
    for (int n = 0; n < N_; n++) acc += h2f(base[(long)n*H_]);
    embb[(long)row*H_ + hh] = f2h(acc * (1.f / N_));
}

// ---------------- LSTM scan: 256 thr, thread=(hh,gatepair), 1 shfl_xor pair ----
// tid = hh*2 + gp; gp=0 -> gates i,f; gp=1 -> gates g,o. 4 waves, 1 barrier/step.
__global__ __launch_bounds__(256) void lstm_scan_k(
    const float* __restrict__ pre,            // [2][T*B][2][256] permuted
    const unsigned int* __restrict__ wpkbuf,  // [2][2][64][256] packed f16 pairs
    float* __restrict__ out,                  // [T*B][256] f32 (nullable)
    ushort* __restrict__ outb)                // [T*B][256] f16 (nullable)
{
    int dir = blockIdx.x >> 5;
    int b   = blockIdx.x & 31;
    int tid = threadIdx.x;           // hh*2 + gp
    int gp  = tid & 1;
    int hh  = tid >> 1;

    __shared__ ushort hbuf[2][H_];   // double-buffered h (f16)
    ((ushort*)hbuf)[tid] = 0;
    float creg = 0.f;                // consistent across the lane pair

    const unsigned int* wpA = wpkbuf + ((long)dir*2 + 0)*64*256;
    const unsigned int* wpB = wpkbuf + ((long)dir*2 + 1)*64*256;
    unsigned int wA[64], wB[64];
    #pragma unroll
    for (int q = 0; q < 64; q++) {
        wA[q] = wpA[q*256 + tid];
        wB[q] = wpB[q*256 + tid];
    }

    const float* pred = pre + (long)dir * T_ * B_ * 512;
    int t = dir ? (T_ - 1) : 0;
    int tstep = dir ? -1 : 1;
    float pvA = pred[(((long)t*B_ + b)*2 + 0)*256 + tid];
    float pvB = pred[(((long)t*B_ + b)*2 + 1)*256 + tid];
    __syncthreads();

    for (int st = 0; st < T_; st++) {
        int tn = t + tstep;
        tn = (tn < 0) ? 0 : ((tn >= T_) ? T_ - 1 : tn);
        float pvAn = pred[(((long)tn*B_ + b)*2 + 0)*256 + tid];
        float pvBn = pred[(((long)tn*B_ + b)*2 + 1)*256 + tid];

        const uint4* h4 = (const uint4*)hbuf[st & 1];
        float a0 = pvA, a1 = 0.f, a2 = 0.f, a3 = 0.f;
        float c0 = pvB, c1 = 0.f, c2 = 0.f, c3 = 0.f;
        #pragma unroll
        for (int jj = 0; jj < 16; jj++) {
            uint4 hv = h4[jj];
            a0 = dot2pk(hv.x, wA[jj*4+0], a0);
            a1 = dot2pk(hv.y, wA[jj*4+1], a1);
            a2 = dot2pk(hv.z, wA[jj*4+2], a2);
            a3 = dot2pk(hv.w, wA[jj*4+3], a3);
            c0 = dot2pk(hv.x, wB[jj*4+0], c0);
            c1 = dot2pk(hv.y, wB[jj*4+1], c1);
            c2 = dot2pk(hv.z, wB[jj*4+2], c2);
            c3 = dot2pk(hv.w, wB[jj*4+3], c3);
        }
        float sA = (a0 + a1) + (a2 + a3);
        float sB = (c0 + c1) + (c2 + c3);
        float oA = __shfl_xor(sA, 1, 64);
        float oB = __shfl_xor(sB, 1, 64);
        float ig = gp ? oA : sA;
        float fg = gp ? oB : sB;
        float gg = gp ? sA : oA;
        float og = gp ? sB : oB;
        float c = sigm(fg) * creg + sigm(ig) * ftanh(gg);
        float h = sigm(og) * ftanh(c);
        creg = c;
        if (gp == 0) {
            hbuf[(st + 1) & 1][hh] = f2h(h);
            long orow = ((long)t*B_ + b)*256 + dir*H_ + hh;
            if (out)  out[orow] = h;
            if (outb) outb[orow] = f2h(h);
        }
        __syncthreads();
        pvA = pvAn; pvB = pvBn;
        t = tn;
    }
}

// ---------------- attention scores (f16 input, T*B blocks) ----------------

__global__ __launch_bounds__(128) void attn_a_k(
    const ushort* __restrict__ out2, const float* __restrict__ w1,
    const float* __restrict__ b1, const float* __restrict__ w2,
    const float* __restrict__ b2v, float* __restrict__ a)
{
    int row = blockIdx.x;
    int j = threadIdx.x;
    const ushort* xr = out2 + (long)row * 256;
    float acc = b1[j];
    for (int k = 0; k < 256; k++) acc += h2f(xr[k]) * w1[k*128 + j];
    float u = tanhf(acc) * w2[j];
    __shared__ float red[128];
    red[j] = u;
    __syncthreads();
    for (int d = 64; d > 0; d >>= 1) {
        if (j < d) red[j] += red[j + d];
        __syncthreads();
    }
    if (j == 0) {
        int t = row / B_, b = row - t*B_;
        a[b*T_ + t] = red[0] + b2v[0];
    }
}

// ---------------- fused softmax-pool + FC head (B blocks, 512 thr) ----------

__global__ __launch_bounds__(512) void pool_head_k(
    const ushort* __restrict__ out2, const float* __restrict__ a,
    const float* __restrict__ w1, const float* __restrict__ b1,
    const float* __restrict__ w2, const float* __restrict__ b2,
    float* __restrict__ outp)
{
    int b = blockIdx.x;
    int tid = threadIdx.x;
    __shared__ float w[T_];
    __shared__ float ws[256];
    __shared__ float r[128];
    __shared__ float y[C_];
    __shared__ float red[512];

    if (tid == 0) {
        float m = -1e30f;
        for (int t = 0; t < T_; t++) m = fmaxf(m, a[b*T_ + t]);
        float s = 0.f;
        for (int t = 0; t < T_; t++) { float e = __expf(a[b*T_ + t] - m); w[t] = e; s += e; }
        float inv = 1.f / s;
        for (int t = 0; t < T_; t++) w[t] *= inv;
    }
    __syncthreads();
    if (tid < 256) {
        float acc = 0.f;
        for (int t = 0; t < T_; t++) acc += w[t] * h2f(out2[((long)t*B_ + b)*256 + tid]);
        ws[tid] = acc;
    }
    __syncthreads();
    if (tid < 128) {
        float acc = b1[tid];
        for (int k = 0; k < 256; k++) acc += ws[k] * w1[k*128 + tid];
        r[tid] = fmaxf(acc, 0.f);
    }
    __syncthreads();
    for (int c = tid; c < C_; c += 512) {
        float acc = b2[c];
        for (int k = 0; k < 128; k++) acc += r[k] * w2[k*C_ + c];
        y[c] = acc;
    }
    __syncthreads();
    float m = -1e30f;
    for (int c = tid; c < C_; c += 512) m = fmaxf(m, y[c]);
    red[tid] = m;
    __syncthreads();
    for (int d = 256; d > 0; d >>= 1) {
        if (tid < d) red[tid] = fmaxf(red[tid], red[tid + d]);
        __syncthreads();
    }
    m = red[0];
    __syncthreads();
    float s = 0.f;
    for (int c = tid; c < C_; c += 512) s += __expf(y[c] - m);
    red[tid] = s;
    __syncthreads();
    for (int d = 256; d > 0; d >>= 1) {
        if (tid < d) red[tid] += red[tid + d];
        __syncthreads();
    }
    float lse = m + logf(red[0]);
    for (int c = tid; c < C_; c += 512) outp[(long)b*C_ + c] = y[c] - lse;
}

// ---------------- launch ----------------

extern "C" void kernel_launch(void* const* d_in, const int* in_sizes, int n_in,
                              void* d_out, int out_size, void* d_ws, size_t ws_size,
                              hipStream_t stream) {
    const float* x        = (const float*)d_in[0];
    const int*   ei       = (const int*)d_in[1];
    const float* gcn_w0   = (const float*)d_in[2];
    const float* gcn_w12  = (const float*)d_in[3];
    const float* gcn_b    = (const float*)d_in[4];
    const float* bn_gamma = (const float*)d_in[5];
    const float* bn_beta  = (const float*)d_in[6];
    const float* bn_mean  = (const float*)d_in[7];
    const float* bn_var   = (const float*)d_in[8];
    const float* wih0     = (const float*)d_in[9];
    const float* whh0     = (const float*)d_in[10];
    const float* bih0     = (const float*)d_in[11];
    const float* bhh0     = (const float*)d_in[12];
    const float* wih1     = (const float*)d_in[13];
    const float* whh1     = (const float*)d_in[14];
    const float* bih1     = (const float*)d_in[15];
    const float* bhh1     = (const float*)d_in[16];
    const float* attn_w1  = (const float*)d_in[17];
    const float* attn_b1  = (const float*)d_in[18];
    const float* attn_w2  = (const float*)d_in[19];
    const float* attn_b2  = (const float*)d_in[20];
    const float* fc1_w    = (const float*)d_in[21];
    const float* fc1_b    = (const float*)d_in[22];
    const float* fc2_w    = (const float*)d_in[23];
    const float* fc2_b    = (const float*)d_in[24];

    char* p = (char*)d_ws;
    auto alloc = [&](size_t bytes) {
        void* r = (void*)p;
        p += (bytes + 255) & ~(size_t)255;
        return r;
    };
    ushort* hbA    = (ushort*)alloc((size_t)M_*H_*2);
    ushort* hbB    = (ushort*)alloc((size_t)M_*H_*2);
    int*   csr_off = (int*)  alloc((size_t)(M_+1)*4);
    unsigned int* csr_pk = (unsigned int*)alloc((size_t)TE_*4);
    float* bn_sc   = (float*)alloc(384*4);
    float* bn_sh   = (float*)alloc(384*4);
    float* bias0   = (float*)alloc(1024*4);
    float* bias1   = (float*)alloc(1024*4);
    ushort* w0t    = (ushort*)alloc((size_t)4096*2);
    ushort* w1t    = (ushort*)alloc((size_t)16384*2);
    ushort* w2t    = (ushort*)alloc((size_t)16384*2);
    unsigned int* wpk0 = (unsigned int*)alloc((size_t)2*64*512*4);
    unsigned int* wpk1 = (unsigned int*)alloc((size_t)2*64*512*4);
    ushort* wih0b  = (ushort*)alloc((size_t)2*512*128*2);
    ushort* wih1b  = (ushort*)alloc((size_t)2*512*256*2);
    ushort* embb   = (ushort*)alloc((size_t)T_*B_*H_*2);
    float* pre     = (float*)alloc((size_t)2*T_*B_*512*4);
    ushort* out1b  = (ushort*)alloc((size_t)T_*B_*256*2);
    ushort* out2b  = (ushort*)alloc((size_t)T_*B_*256*2);
    float* attn_av = (float*)alloc((size_t)B_*T_*4);

    // --- fused CSR build + weight prep in ONE launch (independent work;
    //     wprep blocks fill the 208 CUs csr_build leaves idle) ---
    csr_wprep_k<<<T_ + WPREP_BLOCKS, 1024, 0, stream>>>(
        ei, csr_off, csr_pk,
        gcn_b, bn_gamma, bn_beta, bn_mean, bn_var, bn_sc, bn_sh,
        bih0, bhh0, bias0, bih1, bhh1, bias1,
        gcn_w0, gcn_w12, w0t, w1t, w2t,
        whh0, whh1, wpk0, wpk1,
        wih0, wih1, wih0b, wih1b);

    // --- GCN layer 0 (fully fused: gather + MFMA + BN/ReLU) ---
    gcn0_k<<<M_/64, 256, 0, stream>>>(x, w0t, hbA, csr_off, csr_pk,
                                      bn_sc + 0, bn_sh + 0);
    // --- GCN layer 1 (fused gather + MFMA + BN/ReLU + resid, 8 waves) ---
    gcn_layer_k<<<M_/64, 512, 0, stream>>>(hbA, w1t, hbB, csr_off, csr_pk,
                                           bn_sc + 128, bn_sh + 128);
    // --- GCN layer 2 ---
    gcn_layer_k<<<M_/64, 512, 0, stream>>>(hbB, w2t, hbA, csr_off, csr_pk,
                                           bn_sc + 256, bn_sh + 256);

    // --- mean pool -> embb [T*B,128] f16 ---
    meanpool_k<<<T_*B_, 128, 0, stream>>>(hbA, embb);

    // --- BiLSTM layer 0 ---
    mm_pre_k<128><<<dim3((T_*B_)/64, 4, 2), 256, 0, stream>>>(embb, wih0b, pre, bias0);
    lstm_scan_k<<<64, 256, 0, stream>>>(pre, wpk0, nullptr, out1b);

    // --- BiLSTM layer 1 ---
    mm_pre_k<256><<<dim3((T_*B_)/64, 4, 2), 256, 0, stream>>>(out1b, wih1b, pre, bias1);
    lstm_scan_k<<<64, 256, 0, stream>>>(pre, wpk1, nullptr, out2b);

    // --- attention scores (T*B-block parallelism preserved) ---
    attn_a_k<<<T_*B_, 128, 0, stream>>>(out2b, attn_w1, attn_b1, attn_w2, attn_b2, attn_av);

    // --- fused softmax-pool + FC head (replaces attn_pool + head) ---
    pool_head_k<<<B_, 512, 0, stream>>>(out2b, attn_av,
        fc1_w, fc1_b, fc2_w, fc2_b, (float*)d_out);
}